// Round 5
// baseline (2486.531 us; speedup 1.0000x reference)
//
#include <hip/hip_runtime.h>

#define BB 64
#define SS 1024
#define II 128
#define HH 256
#define OO 128

#if __has_builtin(__builtin_amdgcn_fdot2)
#define HAVE_DOT2 1
#endif

typedef __fp16 h2_t __attribute__((ext_vector_type(2)));

__device__ __forceinline__ float blo(unsigned u) { return __uint_as_float(u << 16); }
__device__ __forceinline__ float bhi(unsigned u) { return __uint_as_float(u & 0xffff0000u); }

__device__ __forceinline__ unsigned pack_bf2(float a, float b) {
    unsigned ua = __float_as_uint(a);
    unsigned ub = __float_as_uint(b);
    ua = (ua + 0x7fffu + ((ua >> 16) & 1u)) >> 16;
    ub = (ub + 0x7fffu + ((ub >> 16) & 1u)) & 0xffff0000u;
    return ua | ub;
}

__device__ __forceinline__ unsigned packh(float a, float b) {
#ifdef HAVE_DOT2
    union { h2_t h; unsigned u; } cv;
    cv.h = __builtin_amdgcn_cvt_pkrtz(a, b);   // v_cvt_pkrtz_f16_f32
    return cv.u;
#else
    return pack_bf2(a, b);
#endif
}

__device__ __forceinline__ float dot2acc(unsigned w, unsigned h, float acc) {
#ifdef HAVE_DOT2
    union { unsigned u; h2_t h; } cw, ch;
    cw.u = w; ch.u = h;
    return __builtin_amdgcn_fdot2(cw.h, ch.h, acc, false);
#else
    return fmaf(blo(w), blo(h), fmaf(bhi(w), bhi(h), acc));
#endif
}

// fast transcendentals: error ~1e-6, below the f16-weight noise floor.
__device__ __forceinline__ float fsigmoid(float x) {
    float e = __builtin_amdgcn_exp2f(-1.4426950408889634f * x);
    return __builtin_amdgcn_rcpf(1.0f + e);
}
__device__ __forceinline__ float ftanh(float x) {
    float e = __builtin_amdgcn_exp2f(2.8853900817779268f * x);   // e^(2x)
    return 1.0f - 2.0f * __builtin_amdgcn_rcpf(1.0f + e);
}

// barrier without vmcnt drain: per-step global store / prefetch stay in flight.
__device__ __forceinline__ void bar_lds() {
    asm volatile("s_waitcnt lgkmcnt(0)\n\ts_barrier" ::: "memory");
}

// ---------------------------------------------------------------------------
// Kernel A: inp[b,t,h] = x[b,t,:] @ W_in[h,:] + (b_in[h] + b_rec[h])
// ---------------------------------------------------------------------------
__global__ __launch_bounds__(256)
void ltc_inproj(const float* __restrict__ x, const float* __restrict__ W_in,
                const float* __restrict__ b_in, const float* __restrict__ b_rec,
                float* __restrict__ inp)
{
    __shared__ float smem[64 * 130];
    const int t = threadIdx.x;
    const int l = t & 63, w = t >> 6;
    const int r0 = blockIdx.x * 64;

    float2* xs2 = (float2*)smem;                // [64][65] float2
    for (int idx = t; idx < 64 * 64; idx += 256) {
        int row = idx >> 6, c2 = idx & 63;
        xs2[row * 65 + c2] = ((const float2*)x)[(size_t)(r0 + row) * 64 + c2];
    }
    __syncthreads();
    float xr[128];
#pragma unroll
    for (int i = 0; i < 64; ++i) {
        float2 v = xs2[l * 65 + i];
        xr[2 * i] = v.x; xr[2 * i + 1] = v.y;
    }
    __syncthreads();

    for (int ph = 0; ph < 2; ++ph) {
        for (int i = 0; i < 32; ++i) {
            const int hh = 128 * ph + 32 * w + i;
            const float4* wr = (const float4*)(W_in + (size_t)hh * II);
            float a0 = b_in[hh] + b_rec[hh], a1 = 0.f, a2 = 0.f, a3 = 0.f;
#pragma unroll
            for (int j = 0; j < 32; ++j) {
                float4 wv = wr[j];
                a0 = fmaf(wv.x, xr[4 * j + 0], a0);
                a1 = fmaf(wv.y, xr[4 * j + 1], a1);
                a2 = fmaf(wv.z, xr[4 * j + 2], a2);
                a3 = fmaf(wv.w, xr[4 * j + 3], a3);
            }
            smem[l * 128 + ((32 * w + i + l) & 127)] = a0 + a1 + a2 + a3;
        }
        __syncthreads();
        for (int k = 0; k < 32; ++k) {
            int idx = k * 256 + t;
            int row = idx >> 7, c = idx & 127;
            inp[(size_t)(r0 + row) * HH + 128 * ph + c] = smem[row * 128 + ((c + row) & 127)];
        }
        __syncthreads();
    }
}

// ---------------------------------------------------------------------------
// Kernel B: persistent recurrence, 96-weight-dword / 4-waves-per-SIMD.
// 64 blocks x 1024 thr (16 waves, 4/SIMD). Thread t -> (r = t>>2, qt = t&3):
// owns row r x k-quarter [qt*64, qt*64+64) for ALL 3 gates = 96 packed dwords.
// Rationale (round-4 post-mortem): every prior round kept 192 weight dwords
// per thread at VGPR_Count=128 -> allocator split the unified file 128V+128A
// and every hot-loop weight read paid a v_accvgpr copy (~2x VALU issue,
// invariant ~2900 cy/step across 4 structural rewrites). 96 dwords + working
// set fits the 128-arch-VGPR budget of 4 waves/SIMD.
//   - h in LDS: 2 x 512B double buffer, uint4 chunks. Per-quarter ROTATION
//     swizzle: logical chunk c of quarter Q stored at Q*8 + ((c+Q)&7).
//     Read: the wave's 4 distinct addresses (one per qt) hit disjoint bank
//     quads every issue; 16 row-quads broadcast the same 4 addrs.
//   - quarter-reduce: __shfl_xor 1,2 = quad DPP (VALU pipe, no LDS)
//   - pointwise redundant on the 4 quad lanes (bitwise lockstep: IEEE add
//     commutes, all lanes reduce to identical sums)
//   - h write-back: row-owner lane (qt==0) does one ds_write_b16 (f16 cvt);
//     2 lanes/dword = 2-way = free. States store: 16x4B contiguous per wave.
//   - ONE lgkm-only barrier per step; inp prefetched 1 step ahead.
// ---------------------------------------------------------------------------
__global__ __launch_bounds__(1024)
void ltc_recurrent(const float* __restrict__ W_rec,
                   const float* __restrict__ W_cg,  const float* __restrict__ b_cg,
                   const float* __restrict__ W_eg,  const float* __restrict__ b_eg,
                   const float* __restrict__ tau,
                   float* __restrict__ st)          // [B,S,H]: inp staged in, states out
{
    const int b = blockIdx.x, t = threadIdx.x;
    const int r = t >> 2, qt = t & 3;               // row 0..255, k-quarter 0..3

    __shared__ __align__(16) uint4 hT[2][32];       // 2 x 512B packed-f16 h, rot-swizzled

    unsigned wR[32], wC[32], wE[32];
#define LOADW(dst, base) { const float4* p4_ = (const float4*)(base); \
    _Pragma("unroll") for (int j = 0; j < 16; ++j) { float4 v_ = p4_[j]; \
        dst[2 * j] = packh(v_.x, v_.y); dst[2 * j + 1] = packh(v_.z, v_.w); } }
    LOADW(wR, W_rec + (size_t)r * HH + qt * 64)
    LOADW(wC, W_cg  + (size_t)r * HH + qt * 64)
    LOADW(wE, W_eg  + (size_t)r * HH + qt * 64)
#undef LOADW

    const float ti = 1.0f / tau[r];
    const float bC = b_cg[r], bE = b_eg[r];

    // precomputed swizzled read offsets (bytes) for this thread's 8 chunks
    int boff[8];
#pragma unroll
    for (int c = 0; c < 8; ++c) boff[c] = (qt * 8 + ((c + qt) & 7)) * 16;

    // precomputed swizzled write byte-offset for this row's f16 slot
    const int d = r >> 1;                            // packed dword 0..127
    const int widx = (d >> 5) * 8 + ((((d >> 2) & 7) + (d >> 5)) & 7);
    const int hoff = widx * 16 + (d & 3) * 4 + (r & 1) * 2;

    float* stb = st + (size_t)b * SS * HH;
    float h = 0.f;                                   // state for row r
    float inpC = stb[r];                             // inp(0, r)

    if (t < 32) hT[0][t] = make_uint4(0u, 0u, 0u, 0u);
    __syncthreads();

    for (int s = 0; s < SS; ++s) {
        const int cur = s & 1, nxt = cur ^ 1;

        float pf = 0.f;
        const bool dopf = (s + 1 < SS);
        if (dopf) pf = stb[(size_t)(s + 1) * HH + r];

        const char* hb = (const char*)hT[cur];
        float aR0 = 0.f, aR1 = 0.f, aC0 = 0.f, aC1 = 0.f, aE0 = 0.f, aE1 = 0.f;
#pragma unroll
        for (int c = 0; c < 8; ++c) {
            uint4 q = *(const uint4*)(hb + boff[c]);
            aR0 = dot2acc(wR[4 * c + 0], q.x, aR0);
            aC0 = dot2acc(wC[4 * c + 0], q.x, aC0);
            aE0 = dot2acc(wE[4 * c + 0], q.x, aE0);
            aR1 = dot2acc(wR[4 * c + 1], q.y, aR1);
            aC1 = dot2acc(wC[4 * c + 1], q.y, aC1);
            aE1 = dot2acc(wE[4 * c + 1], q.y, aE1);
            aR0 = dot2acc(wR[4 * c + 2], q.z, aR0);
            aC0 = dot2acc(wC[4 * c + 2], q.z, aC0);
            aE0 = dot2acc(wE[4 * c + 2], q.z, aE0);
            aR1 = dot2acc(wR[4 * c + 3], q.w, aR1);
            aC1 = dot2acc(wC[4 * c + 3], q.w, aC1);
            aE1 = dot2acc(wE[4 * c + 3], q.w, aE1);
        }
        float aR = aR0 + aR1, aC = aC0 + aC1, aE = aE0 + aE1;
        // reduce across the 4 k-quarters (quad DPP, VALU pipe)
        aR += __shfl_xor(aR, 1); aR += __shfl_xor(aR, 2);
        aC += __shfl_xor(aC, 1); aC += __shfl_xor(aC, 2);
        aE += __shfl_xor(aE, 1); aE += __shfl_xor(aE, 2);

        // pointwise for row r (all 4 quad lanes bitwise-identical)
        float cm = fsigmoid(aC + bC);
        float em = ftanh(aE + bE);
        float p  = inpC + aR;
        float rl = fmaxf(p, 0.f);
        float dh = (rl - h) * ti * cm + 0.1f * em;
        h = fmaf(0.1f, dh, h);

        if (qt == 0) {
            *(_Float16*)((char*)hT[nxt] + hoff) = (_Float16)h;   // ds_write_b16
            stb[(size_t)s * HH + r] = h;
        }
        inpC = pf;
        bar_lds();                                  // hT[nxt] visible for next step
    }
}

// ---------------------------------------------------------------------------
// Kernel C: outputs[row,o] = b_out[o] + states[row,:] @ W_out[o,:]
// ---------------------------------------------------------------------------
__global__ __launch_bounds__(256)
void ltc_out(const float* __restrict__ states, const float* __restrict__ W_out,
             const float* __restrict__ b_out, float* __restrict__ outputs)
{
    __shared__ float smem[64 * 130];
    const int t = threadIdx.x;
    const int l = t & 63, w = t >> 6;
    const int r0 = blockIdx.x * 64;

    float osacc[32];
#pragma unroll
    for (int i = 0; i < 32; ++i) osacc[i] = b_out[32 * w + i];

    float2* xs2 = (float2*)smem;                // [64][65] float2
    for (int ph = 0; ph < 2; ++ph) {
        for (int idx = t; idx < 64 * 64; idx += 256) {
            int row = idx >> 6, c2 = idx & 63;
            xs2[row * 65 + c2] = ((const float2*)states)[(size_t)(r0 + row) * 128 + ph * 64 + c2];
        }
        __syncthreads();
        float xr[128];
#pragma unroll
        for (int i = 0; i < 64; ++i) {
            float2 v = xs2[l * 65 + i];
            xr[2 * i] = v.x; xr[2 * i + 1] = v.y;
        }
        __syncthreads();

        for (int i = 0; i < 32; ++i) {
            const int oo = 32 * w + i;
            const float4* wr = (const float4*)(W_out + (size_t)oo * HH + ph * 128);
            float a0 = 0.f, a1 = 0.f, a2 = 0.f, a3 = 0.f;
#pragma unroll
            for (int j = 0; j < 32; ++j) {
                float4 wv = wr[j];
                a0 = fmaf(wv.x, xr[4 * j + 0], a0);
                a1 = fmaf(wv.y, xr[4 * j + 1], a1);
                a2 = fmaf(wv.z, xr[4 * j + 2], a2);
                a3 = fmaf(wv.w, xr[4 * j + 3], a3);
            }
            osacc[i] += (a0 + a1) + (a2 + a3);
        }
    }

    __syncthreads();
#pragma unroll
    for (int i = 0; i < 32; ++i)
        smem[l * 128 + ((32 * w + i + l) & 127)] = osacc[i];
    __syncthreads();
    for (int k = 0; k < 32; ++k) {
        int idx = k * 256 + t;
        int row = idx >> 7, c = idx & 127;
        outputs[(size_t)(r0 + row) * OO + c] = smem[row * 128 + ((c + row) & 127)];
    }
}

extern "C" void kernel_launch(void* const* d_in, const int* in_sizes, int n_in,
                              void* d_out, int out_size, void* d_ws, size_t ws_size,
                              hipStream_t stream) {
    const float* x      = (const float*)d_in[0];
    const float* W_in   = (const float*)d_in[1];
    const float* b_in   = (const float*)d_in[2];
    const float* W_rec  = (const float*)d_in[3];
    const float* b_rec  = (const float*)d_in[4];
    const float* W_out  = (const float*)d_in[5];
    const float* b_out  = (const float*)d_in[6];
    const float* W_cg   = (const float*)d_in[7];
    const float* b_cg   = (const float*)d_in[8];
    const float* W_eg   = (const float*)d_in[9];
    const float* b_eg   = (const float*)d_in[10];
    const float* tau    = (const float*)d_in[11];

    float* outputs = (float*)d_out;                       // [B,S,O]
    float* states  = outputs + (size_t)BB * SS * OO;      // [B,S,H] (inp staging -> states)

    hipLaunchKernelGGL(ltc_inproj, dim3(BB * SS / 64), dim3(256), 0, stream,
                       x, W_in, b_in, b_rec, states);
    hipLaunchKernelGGL(ltc_recurrent, dim3(BB), dim3(1024), 0, stream,
                       W_rec, W_cg, b_cg, W_eg, b_eg, tau, states);
    hipLaunchKernelGGL(ltc_out, dim3(BB * SS / 64), dim3(256), 0, stream,
                       states, W_out, b_out, outputs);
}

// Round 6
// 2189.810 us; speedup vs baseline: 1.1355x; 1.1355x over previous
//
#include <hip/hip_runtime.h>

#define BB 64
#define SS 1024
#define II 128
#define HH 256
#define OO 128

#if __has_builtin(__builtin_amdgcn_fdot2)
#define HAVE_DOT2 1
#endif

typedef __fp16 h2_t __attribute__((ext_vector_type(2)));

__device__ __forceinline__ float blo(unsigned u) { return __uint_as_float(u << 16); }
__device__ __forceinline__ float bhi(unsigned u) { return __uint_as_float(u & 0xffff0000u); }

__device__ __forceinline__ unsigned pack_bf2(float a, float b) {
    unsigned ua = __float_as_uint(a);
    unsigned ub = __float_as_uint(b);
    ua = (ua + 0x7fffu + ((ua >> 16) & 1u)) >> 16;
    ub = (ub + 0x7fffu + ((ub >> 16) & 1u)) & 0xffff0000u;
    return ua | ub;
}

__device__ __forceinline__ unsigned packh(float a, float b) {
#ifdef HAVE_DOT2
    union { h2_t h; unsigned u; } cv;
    cv.h = __builtin_amdgcn_cvt_pkrtz(a, b);   // v_cvt_pkrtz_f16_f32
    return cv.u;
#else
    return pack_bf2(a, b);
#endif
}

__device__ __forceinline__ float dot2acc(unsigned w, unsigned h, float acc) {
#ifdef HAVE_DOT2
    union { unsigned u; h2_t h; } cw, ch;
    cw.u = w; ch.u = h;
    return __builtin_amdgcn_fdot2(cw.h, ch.h, acc, false);
#else
    return fmaf(blo(w), blo(h), fmaf(bhi(w), bhi(h), acc));
#endif
}

// fast transcendentals: error ~1e-6, below the f16-weight noise floor.
__device__ __forceinline__ float fsigmoid(float x) {
    float e = __builtin_amdgcn_exp2f(-1.4426950408889634f * x);
    return __builtin_amdgcn_rcpf(1.0f + e);
}
__device__ __forceinline__ float ftanh(float x) {
    float e = __builtin_amdgcn_exp2f(2.8853900817779268f * x);   // e^(2x)
    return 1.0f - 2.0f * __builtin_amdgcn_rcpf(1.0f + e);
}

// barrier without vmcnt drain: per-step global store / prefetch stay in flight.
__device__ __forceinline__ void bar_lds() {
    asm volatile("s_waitcnt lgkmcnt(0)\n\ts_barrier" ::: "memory");
}

// ---------------------------------------------------------------------------
// Kernel A: inp[b,t,h] = x[b,t,:] @ W_in[h,:] + (b_in[h] + b_rec[h])
// ---------------------------------------------------------------------------
__global__ __launch_bounds__(256)
void ltc_inproj(const float* __restrict__ x, const float* __restrict__ W_in,
                const float* __restrict__ b_in, const float* __restrict__ b_rec,
                float* __restrict__ inp)
{
    __shared__ float smem[64 * 130];
    const int t = threadIdx.x;
    const int l = t & 63, w = t >> 6;
    const int r0 = blockIdx.x * 64;

    float2* xs2 = (float2*)smem;                // [64][65] float2
    for (int idx = t; idx < 64 * 64; idx += 256) {
        int row = idx >> 6, c2 = idx & 63;
        xs2[row * 65 + c2] = ((const float2*)x)[(size_t)(r0 + row) * 64 + c2];
    }
    __syncthreads();
    float xr[128];
#pragma unroll
    for (int i = 0; i < 64; ++i) {
        float2 v = xs2[l * 65 + i];
        xr[2 * i] = v.x; xr[2 * i + 1] = v.y;
    }
    __syncthreads();

    for (int ph = 0; ph < 2; ++ph) {
        for (int i = 0; i < 32; ++i) {
            const int hh = 128 * ph + 32 * w + i;
            const float4* wr = (const float4*)(W_in + (size_t)hh * II);
            float a0 = b_in[hh] + b_rec[hh], a1 = 0.f, a2 = 0.f, a3 = 0.f;
#pragma unroll
            for (int j = 0; j < 32; ++j) {
                float4 wv = wr[j];
                a0 = fmaf(wv.x, xr[4 * j + 0], a0);
                a1 = fmaf(wv.y, xr[4 * j + 1], a1);
                a2 = fmaf(wv.z, xr[4 * j + 2], a2);
                a3 = fmaf(wv.w, xr[4 * j + 3], a3);
            }
            smem[l * 128 + ((32 * w + i + l) & 127)] = a0 + a1 + a2 + a3;
        }
        __syncthreads();
        for (int k = 0; k < 32; ++k) {
            int idx = k * 256 + t;
            int row = idx >> 7, c = idx & 127;
            inp[(size_t)(r0 + row) * HH + 128 * ph + c] = smem[row * 128 + ((c + row) & 127)];
        }
        __syncthreads();
    }
}

// ---------------------------------------------------------------------------
// Kernel B: persistent recurrence — round-2 structure (best measured: 1145us)
// with ONE change: __launch_bounds__(512, 1).
// Round-5 diagnosis: at the default occupancy target the allocator splits the
// unified register file 128 arch + 128 acc and parks the 192 packed-weight
// dwords in AGPRs; v_dot2 (VOP3P) then pays a v_accvgpr_read per weight
// operand (~+190 VALU inst/thread/step — matches the measured ~2x VALU issue
// inflation that has been invariant across all 5 structural rewrites).
// (512,1) raises the arch-VGPR budget to 256/wave (block = 8 waves = 2/SIMD
// co-resident x 256 = 512 = full unified file), fitting weights + working set
// entirely in arch VGPRs with zero AGPR traffic.
// ---------------------------------------------------------------------------
__global__ __launch_bounds__(512, 1)
void ltc_recurrent(const float* __restrict__ W_rec,
                   const float* __restrict__ W_cg,  const float* __restrict__ b_cg,
                   const float* __restrict__ W_eg,  const float* __restrict__ b_eg,
                   const float* __restrict__ tau,
                   float* __restrict__ st)          // [B,S,H]: inp staged in, states out
{
    const int b = blockIdx.x, t = threadIdx.x;
    const int r = t >> 1, half = t & 1;

    // [buf][132]: dwords 0..63 = packed pairs 0..63, pad 64..67, 68..131 = pairs 64..127
    __shared__ __align__(16) unsigned h_p[2][132];

    unsigned wR[64], wC[64], wE[64];
    {
        const float4* R4 = (const float4*)(W_rec + (size_t)r * HH + half * 128);
        const float4* C4 = (const float4*)(W_cg  + (size_t)r * HH + half * 128);
        const float4* E4 = (const float4*)(W_eg  + (size_t)r * HH + half * 128);
#pragma unroll
        for (int j = 0; j < 32; ++j) {
            float4 v = R4[j]; wR[2 * j] = packh(v.x, v.y); wR[2 * j + 1] = packh(v.z, v.w);
        }
#pragma unroll
        for (int j = 0; j < 32; ++j) {
            float4 v = C4[j]; wC[2 * j] = packh(v.x, v.y); wC[2 * j + 1] = packh(v.z, v.w);
        }
#pragma unroll
        for (int j = 0; j < 32; ++j) {
            float4 v = E4[j]; wE[2 * j] = packh(v.x, v.y); wE[2 * j + 1] = packh(v.z, v.w);
        }
    }

    const float ti = 1.0f / tau[r];
    const float bC = b_cg[r], bE = b_eg[r];

    float* stb = st + (size_t)b * SS * HH;
    float hr = 0.f;                    // f32 state for row r
    float inpC = stb[r];               // inp(0, r) — b_in+b_rec already folded

    if (t < 132) h_p[0][t] = 0u;
    bar_lds();

    for (int s = 0; s < SS; ++s) {
        float inpN = 0.f;
        if (s + 1 < SS) inpN = stb[(size_t)(s + 1) * HH + r];

        const uint4* hp4 = (const uint4*)(h_p[s & 1]) + half * 17;  // 17 uint4 = 68 dwords
        float aR0 = 0.f, aR1 = 0.f, aC0 = 0.f, aC1 = 0.f, aE0 = 0.f, aE1 = 0.f;
#pragma unroll
        for (int c = 0; c < 4; ++c) {                   // 4 chunks x 16 packed dwords
            uint4 q0 = hp4[c * 4 + 0], q1 = hp4[c * 4 + 1];
            uint4 q2 = hp4[c * 4 + 2], q3 = hp4[c * 4 + 3];
#define DOTQ(Q, k0, k1, k2, k3) \
            aR0 = dot2acc(wR[c * 16 + k0], Q.x, aR0); \
            aC0 = dot2acc(wC[c * 16 + k0], Q.x, aC0); \
            aE0 = dot2acc(wE[c * 16 + k0], Q.x, aE0); \
            aR1 = dot2acc(wR[c * 16 + k1], Q.y, aR1); \
            aC1 = dot2acc(wC[c * 16 + k1], Q.y, aC1); \
            aE1 = dot2acc(wE[c * 16 + k1], Q.y, aE1); \
            aR0 = dot2acc(wR[c * 16 + k2], Q.z, aR0); \
            aC0 = dot2acc(wC[c * 16 + k2], Q.z, aC0); \
            aE0 = dot2acc(wE[c * 16 + k2], Q.z, aE0); \
            aR1 = dot2acc(wR[c * 16 + k3], Q.w, aR1); \
            aC1 = dot2acc(wC[c * 16 + k3], Q.w, aC1); \
            aE1 = dot2acc(wE[c * 16 + k3], Q.w, aE1);
            DOTQ(q0, 0, 1, 2, 3)
            DOTQ(q1, 4, 5, 6, 7)
            DOTQ(q2, 8, 9, 10, 11)
            DOTQ(q3, 12, 13, 14, 15)
#undef DOTQ
        }
        float aR = aR0 + aR1, aC = aC0 + aC1, aE = aE0 + aE1;
        aR += __shfl_xor(aR, 1);                         // cross-half reduce in-wave
        aC += __shfl_xor(aC, 1);
        aE += __shfl_xor(aE, 1);

        // pointwise for row r (both half-lanes compute identical values)
        float cm = fsigmoid(aC + bC);
        float em = ftanh(aE + bE);
        float p  = inpC + aR;
        float rl = fmaxf(p, 0.f);
        float dh = (rl - hr) * ti * cm + 0.1f * em;
        hr = fmaf(0.1f, dh, hr);

        // pack rows (r, r+1): t%4==0 threads (r even, half 0) grab neighbor h
        float hnb = __shfl_xor(hr, 2);
        if ((t & 3) == 0) {
            int wi = t >> 2;                             // pair index 0..127
            int wo = wi + ((wi >> 6) << 2);              // +4 pad for pairs >= 64
            h_p[(s + 1) & 1][wo] = packh(hr, hnb);
            float2 hv; hv.x = hr; hv.y = hnb;
            ((float2*)(stb + (size_t)s * HH))[wi] = hv;
        }
        inpC = inpN;
        bar_lds();                                       // h_p[(s+1)&1] visible
    }
}

// ---------------------------------------------------------------------------
// Kernel C: outputs[row,o] = b_out[o] + states[row,:] @ W_out[o,:]
// ---------------------------------------------------------------------------
__global__ __launch_bounds__(256)
void ltc_out(const float* __restrict__ states, const float* __restrict__ W_out,
             const float* __restrict__ b_out, float* __restrict__ outputs)
{
    __shared__ float smem[64 * 130];
    const int t = threadIdx.x;
    const int l = t & 63, w = t >> 6;
    const int r0 = blockIdx.x * 64;

    float osacc[32];
#pragma unroll
    for (int i = 0; i < 32; ++i) osacc[i] = b_out[32 * w + i];

    float2* xs2 = (float2*)smem;                // [64][65] float2
    for (int ph = 0; ph < 2; ++ph) {
        for (int idx = t; idx < 64 * 64; idx += 256) {
            int row = idx >> 6, c2 = idx & 63;
            xs2[row * 65 + c2] = ((const float2*)states)[(size_t)(r0 + row) * 128 + ph * 64 + c2];
        }
        __syncthreads();
        float xr[128];
#pragma unroll
        for (int i = 0; i < 64; ++i) {
            float2 v = xs2[l * 65 + i];
            xr[2 * i] = v.x; xr[2 * i + 1] = v.y;
        }
        __syncthreads();

        for (int i = 0; i < 32; ++i) {
            const int oo = 32 * w + i;
            const float4* wr = (const float4*)(W_out + (size_t)oo * HH + ph * 128);
            float a0 = 0.f, a1 = 0.f, a2 = 0.f, a3 = 0.f;
#pragma unroll
            for (int j = 0; j < 32; ++j) {
                float4 wv = wr[j];
                a0 = fmaf(wv.x, xr[4 * j + 0], a0);
                a1 = fmaf(wv.y, xr[4 * j + 1], a1);
                a2 = fmaf(wv.z, xr[4 * j + 2], a2);
                a3 = fmaf(wv.w, xr[4 * j + 3], a3);
            }
            osacc[i] += (a0 + a1) + (a2 + a3);
        }
    }

    __syncthreads();
#pragma unroll
    for (int i = 0; i < 32; ++i)
        smem[l * 128 + ((32 * w + i + l) & 127)] = osacc[i];
    __syncthreads();
    for (int k = 0; k < 32; ++k) {
        int idx = k * 256 + t;
        int row = idx >> 7, c = idx & 127;
        outputs[(size_t)(r0 + row) * OO + c] = smem[row * 128 + ((c + row) & 127)];
    }
}

extern "C" void kernel_launch(void* const* d_in, const int* in_sizes, int n_in,
                              void* d_out, int out_size, void* d_ws, size_t ws_size,
                              hipStream_t stream) {
    const float* x      = (const float*)d_in[0];
    const float* W_in   = (const float*)d_in[1];
    const float* b_in   = (const float*)d_in[2];
    const float* W_rec  = (const float*)d_in[3];
    const float* b_rec  = (const float*)d_in[4];
    const float* W_out  = (const float*)d_in[5];
    const float* b_out  = (const float*)d_in[6];
    const float* W_cg   = (const float*)d_in[7];
    const float* b_cg   = (const float*)d_in[8];
    const float* W_eg   = (const float*)d_in[9];
    const float* b_eg   = (const float*)d_in[10];
    const float* tau    = (const float*)d_in[11];

    float* outputs = (float*)d_out;                       // [B,S,O]
    float* states  = outputs + (size_t)BB * SS * OO;      // [B,S,H] (inp staging -> states)

    hipLaunchKernelGGL(ltc_inproj, dim3(BB * SS / 64), dim3(256), 0, stream,
                       x, W_in, b_in, b_rec, states);
    hipLaunchKernelGGL(ltc_recurrent, dim3(BB), dim3(512), 0, stream,
                       W_rec, W_cg, b_cg, W_eg, b_eg, tau, states);
    hipLaunchKernelGGL(ltc_out, dim3(BB * SS / 64), dim3(256), 0, stream,
                       states, W_out, b_out, outputs);
}

// Round 7
// 1675.714 us; speedup vs baseline: 1.4839x; 1.3068x over previous
//
#include <hip/hip_runtime.h>

#define BB 64
#define SS 1024
#define II 128
#define HH 256
#define OO 128

#if __has_builtin(__builtin_amdgcn_fdot2)
#define HAVE_DOT2 1
#endif

typedef __fp16 h2_t __attribute__((ext_vector_type(2)));

__device__ __forceinline__ float blo(unsigned u) { return __uint_as_float(u << 16); }
__device__ __forceinline__ float bhi(unsigned u) { return __uint_as_float(u & 0xffff0000u); }

__device__ __forceinline__ unsigned pack_bf2(float a, float b) {
    unsigned ua = __float_as_uint(a);
    unsigned ub = __float_as_uint(b);
    ua = (ua + 0x7fffu + ((ua >> 16) & 1u)) >> 16;
    ub = (ub + 0x7fffu + ((ub >> 16) & 1u)) & 0xffff0000u;
    return ua | ub;
}

__device__ __forceinline__ unsigned packh(float a, float b) {
#ifdef HAVE_DOT2
    union { h2_t h; unsigned u; } cv;
    cv.h = __builtin_amdgcn_cvt_pkrtz(a, b);   // v_cvt_pkrtz_f16_f32
    return cv.u;
#else
    return pack_bf2(a, b);
#endif
}

__device__ __forceinline__ float dot2acc(unsigned w, unsigned h, float acc) {
#ifdef HAVE_DOT2
    union { unsigned u; h2_t h; } cw, ch;
    cw.u = w; ch.u = h;
    return __builtin_amdgcn_fdot2(cw.h, ch.h, acc, false);
#else
    return fmaf(blo(w), blo(h), fmaf(bhi(w), bhi(h), acc));
#endif
}

// fast transcendentals: error ~1e-6, below the f16-weight noise floor.
__device__ __forceinline__ float fsigmoid(float x) {
    float e = __builtin_amdgcn_exp2f(-1.4426950408889634f * x);
    return __builtin_amdgcn_rcpf(1.0f + e);
}
__device__ __forceinline__ float ftanh(float x) {
    float e = __builtin_amdgcn_exp2f(2.8853900817779268f * x);   // e^(2x)
    return 1.0f - 2.0f * __builtin_amdgcn_rcpf(1.0f + e);
}

// barrier without vmcnt drain: per-step global store / prefetch stay in flight.
__device__ __forceinline__ void bar_lds() {
    asm volatile("s_waitcnt lgkmcnt(0)\n\ts_barrier" ::: "memory");
}

// ---------------------------------------------------------------------------
// Kernel A: inp[b,t,h] = x[b,t,:] @ W_in[h,:] + (b_in[h] + b_rec[h])
// hh is wave-uniform but uniformity analysis can't see it (t>>6 divergent);
// readfirstlane makes the W address provably uniform -> SMEM s_load path
// (W_in is __restrict__ const -> noclobber provable), killing the 2048
// per-lane redundant VMEM loads per thread.
// ---------------------------------------------------------------------------
__global__ __launch_bounds__(256)
void ltc_inproj(const float* __restrict__ x, const float* __restrict__ W_in,
                const float* __restrict__ b_in, const float* __restrict__ b_rec,
                float* __restrict__ inp)
{
    __shared__ float smem[64 * 130];
    const int t = threadIdx.x;
    const int l = t & 63, w = t >> 6;
    const int r0 = blockIdx.x * 64;

    float2* xs2 = (float2*)smem;                // [64][65] float2
    for (int idx = t; idx < 64 * 64; idx += 256) {
        int row = idx >> 6, c2 = idx & 63;
        xs2[row * 65 + c2] = ((const float2*)x)[(size_t)(r0 + row) * 64 + c2];
    }
    __syncthreads();
    float xr[128];
#pragma unroll
    for (int i = 0; i < 64; ++i) {
        float2 v = xs2[l * 65 + i];
        xr[2 * i] = v.x; xr[2 * i + 1] = v.y;
    }
    __syncthreads();

    for (int ph = 0; ph < 2; ++ph) {
        for (int i = 0; i < 32; ++i) {
            const int hh = __builtin_amdgcn_readfirstlane(128 * ph + 32 * w + i);
            const float4* wr = (const float4*)(W_in + (size_t)hh * II);
            float a0 = b_in[hh] + b_rec[hh], a1 = 0.f, a2 = 0.f, a3 = 0.f;
#pragma unroll
            for (int j = 0; j < 32; ++j) {
                float4 wv = wr[j];
                a0 = fmaf(wv.x, xr[4 * j + 0], a0);
                a1 = fmaf(wv.y, xr[4 * j + 1], a1);
                a2 = fmaf(wv.z, xr[4 * j + 2], a2);
                a3 = fmaf(wv.w, xr[4 * j + 3], a3);
            }
            smem[l * 128 + (((hh & 127) + l) & 127)] = a0 + a1 + a2 + a3;
        }
        __syncthreads();
        for (int k = 0; k < 32; ++k) {
            int idx = k * 256 + t;
            int row = idx >> 7, c = idx & 127;
            inp[(size_t)(r0 + row) * HH + 128 * ph + c] = smem[row * 128 + ((c + row) & 127)];
        }
        __syncthreads();
    }
}

// ---------------------------------------------------------------------------
// Kernel B: persistent recurrence, gate-split / 768 threads (12 waves,
// 3 waves/SIMD forced by block shape -> 170-reg total budget per wave).
// Wave w -> (gate g = w%3, k-quarter kq = w/3). Lane l owns rows
// {l, l+64, l+128, l+192} x k-slice [kq*64, kq*64+64) for ONE gate:
//   128 packed-weight dwords + 8 acc + ~25 misc ~= 160 <= 170 -> whole
//   working set in ARCH VGPRs (kills the 6-round AGPR/copy tax invariant).
// h reads: 8 x ds_read_b128, wave-uniform address -> LDS broadcast,
// conflict-free, 96 wave-reads/CU/step. Gate partials -> part[3][4][256];
// pointwise on threads<256 between two lgkm-only barriers.
// ---------------------------------------------------------------------------
__global__ __launch_bounds__(768)
void ltc_recurrent(const float* __restrict__ W_rec,
                   const float* __restrict__ W_cg,  const float* __restrict__ b_cg,
                   const float* __restrict__ W_eg,  const float* __restrict__ b_eg,
                   const float* __restrict__ tau,
                   float* __restrict__ st)          // [B,S,H]: inp staged in, states out
{
    const int b = blockIdx.x, t = threadIdx.x;
    const int wv = t >> 6, l = t & 63;
    const int g = wv % 3;                            // 0=rec, 1=cg, 2=eg
    const int kq = wv / 3;                           // k-quarter 0..3
    const int rp = t & 255;                          // pointwise row (t<256)

    __shared__ __align__(16) unsigned h_p[2][128];   // packed f16 h, double-buffered
    __shared__ __align__(16) float part[3][4][256];  // [gate][kq][row]

    const float* Wg = (g == 0) ? W_rec : (g == 1) ? W_cg : W_eg;

    unsigned wgt[4][32];                             // 128 dwords
#pragma unroll
    for (int rr = 0; rr < 4; ++rr) {
        const float4* p4 = (const float4*)(Wg + (size_t)(rr * 64 + l) * HH + kq * 64);
#pragma unroll
        for (int j = 0; j < 16; ++j) {
            float4 v = p4[j];
            wgt[rr][2 * j]     = packh(v.x, v.y);
            wgt[rr][2 * j + 1] = packh(v.z, v.w);
        }
    }

    float* stb = st + (size_t)b * SS * HH;
    float h = 0.f, inpC = 0.f, ti = 0.f, bC = 0.f, bE = 0.f;
    if (t < 256) {
        ti = 1.0f / tau[rp];
        bC = b_cg[rp]; bE = b_eg[rp];
        inpC = stb[rp];                              // inp(0, rp); b_in+b_rec folded
    }
    if (t < 128) h_p[0][t] = 0u;
    __syncthreads();

    for (int s = 0; s < SS; ++s) {
        const int cur = s & 1, nxt = cur ^ 1;

        float pf = 0.f;
        if (t < 256 && s + 1 < SS) pf = stb[(size_t)(s + 1) * HH + rp];

        // ---- phase 1: dots (all 12 waves) ----
        const uint4* hp4 = (const uint4*)h_p[cur] + kq * 8;   // wave-uniform addr
        float a00 = 0.f, a01 = 0.f, a10 = 0.f, a11 = 0.f;
        float a20 = 0.f, a21 = 0.f, a30 = 0.f, a31 = 0.f;
#pragma unroll
        for (int c = 0; c < 8; ++c) {
            uint4 q = hp4[c];
            a00 = dot2acc(wgt[0][4 * c + 0], q.x, a00);
            a01 = dot2acc(wgt[0][4 * c + 1], q.y, a01);
            a10 = dot2acc(wgt[1][4 * c + 0], q.x, a10);
            a11 = dot2acc(wgt[1][4 * c + 1], q.y, a11);
            a20 = dot2acc(wgt[2][4 * c + 0], q.x, a20);
            a21 = dot2acc(wgt[2][4 * c + 1], q.y, a21);
            a30 = dot2acc(wgt[3][4 * c + 0], q.x, a30);
            a31 = dot2acc(wgt[3][4 * c + 1], q.y, a31);
            a00 = dot2acc(wgt[0][4 * c + 2], q.z, a00);
            a01 = dot2acc(wgt[0][4 * c + 3], q.w, a01);
            a10 = dot2acc(wgt[1][4 * c + 2], q.z, a10);
            a11 = dot2acc(wgt[1][4 * c + 3], q.w, a11);
            a20 = dot2acc(wgt[2][4 * c + 2], q.z, a20);
            a21 = dot2acc(wgt[2][4 * c + 3], q.w, a21);
            a30 = dot2acc(wgt[3][4 * c + 2], q.z, a30);
            a31 = dot2acc(wgt[3][4 * c + 3], q.w, a31);
        }
        part[g][kq][l]       = a00 + a01;
        part[g][kq][l + 64]  = a10 + a11;
        part[g][kq][l + 128] = a20 + a21;
        part[g][kq][l + 192] = a30 + a31;
        bar_lds();                                   // partials visible

        // ---- phase 2: pointwise (threads < 256; others wait at barrier) ----
        if (t < 256) {
            float sR = (part[0][0][rp] + part[0][1][rp]) + (part[0][2][rp] + part[0][3][rp]);
            float sC = (part[1][0][rp] + part[1][1][rp]) + (part[1][2][rp] + part[1][3][rp]);
            float sE = (part[2][0][rp] + part[2][1][rp]) + (part[2][2][rp] + part[2][3][rp]);
            float cm = fsigmoid(sC + bC);
            float em = ftanh(sE + bE);
            float p  = inpC + sR;                    // rec bias folded into inp
            float rl = fmaxf(p, 0.f);
            float dh = (rl - h) * ti * cm + 0.1f * em;
            h = fmaf(0.1f, dh, h);

            float hnb = __shfl_xor(h, 1);            // pair rows (2k, 2k+1)
            stb[(size_t)s * HH + rp] = h;            // coalesced f32 states
            if ((t & 1) == 0)
                h_p[nxt][rp >> 1] = packh(h, hnb);   // conflict-free b32 writes
            inpC = pf;
        }
        bar_lds();                                   // h_p[nxt] visible
    }
}

// ---------------------------------------------------------------------------
// Kernel C: outputs[row,o] = b_out[o] + states[row,:] @ W_out[o,:]
// Same readfirstlane scalar-W trick as kernel A.
// ---------------------------------------------------------------------------
__global__ __launch_bounds__(256)
void ltc_out(const float* __restrict__ states, const float* __restrict__ W_out,
             const float* __restrict__ b_out, float* __restrict__ outputs)
{
    __shared__ float smem[64 * 130];
    const int t = threadIdx.x;
    const int l = t & 63, w = t >> 6;
    const int r0 = blockIdx.x * 64;

    float osacc[32];
#pragma unroll
    for (int i = 0; i < 32; ++i)
        osacc[i] = b_out[__builtin_amdgcn_readfirstlane(32 * w + i)];

    float2* xs2 = (float2*)smem;                // [64][65] float2
    for (int ph = 0; ph < 2; ++ph) {
        for (int idx = t; idx < 64 * 64; idx += 256) {
            int row = idx >> 6, c2 = idx & 63;
            xs2[row * 65 + c2] = ((const float2*)states)[(size_t)(r0 + row) * 128 + ph * 64 + c2];
        }
        __syncthreads();
        float xr[128];
#pragma unroll
        for (int i = 0; i < 64; ++i) {
            float2 v = xs2[l * 65 + i];
            xr[2 * i] = v.x; xr[2 * i + 1] = v.y;
        }
        __syncthreads();

        for (int i = 0; i < 32; ++i) {
            const int oo = __builtin_amdgcn_readfirstlane(32 * w + i);
            const float4* wr = (const float4*)(W_out + (size_t)oo * HH + ph * 128);
            float a0 = 0.f, a1 = 0.f, a2 = 0.f, a3 = 0.f;
#pragma unroll
            for (int j = 0; j < 32; ++j) {
                float4 wv = wr[j];
                a0 = fmaf(wv.x, xr[4 * j + 0], a0);
                a1 = fmaf(wv.y, xr[4 * j + 1], a1);
                a2 = fmaf(wv.z, xr[4 * j + 2], a2);
                a3 = fmaf(wv.w, xr[4 * j + 3], a3);
            }
            osacc[i] += (a0 + a1) + (a2 + a3);
        }
    }

    __syncthreads();
#pragma unroll
    for (int i = 0; i < 32; ++i)
        smem[l * 128 + ((32 * w + i + l) & 127)] = osacc[i];
    __syncthreads();
    for (int k = 0; k < 32; ++k) {
        int idx = k * 256 + t;
        int row = idx >> 7, c = idx & 127;
        outputs[(size_t)(r0 + row) * OO + c] = smem[row * 128 + ((c + row) & 127)];
    }
}

extern "C" void kernel_launch(void* const* d_in, const int* in_sizes, int n_in,
                              void* d_out, int out_size, void* d_ws, size_t ws_size,
                              hipStream_t stream) {
    const float* x      = (const float*)d_in[0];
    const float* W_in   = (const float*)d_in[1];
    const float* b_in   = (const float*)d_in[2];
    const float* W_rec  = (const float*)d_in[3];
    const float* b_rec  = (const float*)d_in[4];
    const float* W_out  = (const float*)d_in[5];
    const float* b_out  = (const float*)d_in[6];
    const float* W_cg   = (const float*)d_in[7];
    const float* b_cg   = (const float*)d_in[8];
    const float* W_eg   = (const float*)d_in[9];
    const float* b_eg   = (const float*)d_in[10];
    const float* tau    = (const float*)d_in[11];

    float* outputs = (float*)d_out;                       // [B,S,O]
    float* states  = outputs + (size_t)BB * SS * OO;      // [B,S,H] (inp staging -> states)

    hipLaunchKernelGGL(ltc_inproj, dim3(BB * SS / 64), dim3(256), 0, stream,
                       x, W_in, b_in, b_rec, states);
    hipLaunchKernelGGL(ltc_recurrent, dim3(BB), dim3(768), 0, stream,
                       W_rec, W_cg, b_cg, W_eg, b_eg, tau, states);
    hipLaunchKernelGGL(ltc_out, dim3(BB * SS / 64), dim3(256), 0, stream,
                       states, W_out, b_out, outputs);
}

// Round 8
// 1663.904 us; speedup vs baseline: 1.4944x; 1.0071x over previous
//
#include <hip/hip_runtime.h>
#include <hip/hip_fp16.h>

#define BB 64
#define SS 1024
#define II 128
#define HH 256
#define OO 128

#if __has_builtin(__builtin_amdgcn_fdot2)
#define HAVE_DOT2 1
#endif

typedef __fp16 h2_t __attribute__((ext_vector_type(2)));

__device__ __forceinline__ unsigned packh(float a, float b) {
    union { h2_t h; unsigned u; } cv;
    cv.h = __builtin_amdgcn_cvt_pkrtz(a, b);   // v_cvt_pkrtz_f16_f32
    return cv.u;
}

__device__ __forceinline__ __half2 u2h(unsigned u) {
    union { unsigned u; __half2 h; } c; c.u = u; return c.h;
}

// fast transcendentals: error ~1e-6, below the f16-weight noise floor.
__device__ __forceinline__ float fsigmoid(float x) {
    float e = __builtin_amdgcn_exp2f(-1.4426950408889634f * x);
    return __builtin_amdgcn_rcpf(1.0f + e);
}
__device__ __forceinline__ float ftanh(float x) {
    float e = __builtin_amdgcn_exp2f(2.8853900817779268f * x);   // e^(2x)
    return 1.0f - 2.0f * __builtin_amdgcn_rcpf(1.0f + e);
}

// barrier without vmcnt drain: per-step global store / prefetch stay in flight.
__device__ __forceinline__ void bar_lds() {
    asm volatile("s_waitcnt lgkmcnt(0)\n\ts_barrier" ::: "memory");
}

// ---------------------------------------------------------------------------
// Kernel A: inp[b,t,h] = x[b,t,:] @ W_in[h,:] + (b_in[h] + b_rec[h])
// readfirstlane makes the W address provably wave-uniform -> s_load path
// (round-7 verified: A+C dropped 1073 -> 399us).
// ---------------------------------------------------------------------------
__global__ __launch_bounds__(256)
void ltc_inproj(const float* __restrict__ x, const float* __restrict__ W_in,
                const float* __restrict__ b_in, const float* __restrict__ b_rec,
                float* __restrict__ inp)
{
    __shared__ float smem[64 * 130];
    const int t = threadIdx.x;
    const int l = t & 63, w = t >> 6;
    const int r0 = blockIdx.x * 64;

    float2* xs2 = (float2*)smem;                // [64][65] float2
    for (int idx = t; idx < 64 * 64; idx += 256) {
        int row = idx >> 6, c2 = idx & 63;
        xs2[row * 65 + c2] = ((const float2*)x)[(size_t)(r0 + row) * 64 + c2];
    }
    __syncthreads();
    float xr[128];
#pragma unroll
    for (int i = 0; i < 64; ++i) {
        float2 v = xs2[l * 65 + i];
        xr[2 * i] = v.x; xr[2 * i + 1] = v.y;
    }
    __syncthreads();

    for (int ph = 0; ph < 2; ++ph) {
        for (int i = 0; i < 32; ++i) {
            const int hh = __builtin_amdgcn_readfirstlane(128 * ph + 32 * w + i);
            const float4* wr = (const float4*)(W_in + (size_t)hh * II);
            float a0 = b_in[hh] + b_rec[hh], a1 = 0.f, a2 = 0.f, a3 = 0.f;
#pragma unroll
            for (int j = 0; j < 32; ++j) {
                float4 wv = wr[j];
                a0 = fmaf(wv.x, xr[4 * j + 0], a0);
                a1 = fmaf(wv.y, xr[4 * j + 1], a1);
                a2 = fmaf(wv.z, xr[4 * j + 2], a2);
                a3 = fmaf(wv.w, xr[4 * j + 3], a3);
            }
            smem[l * 128 + (((hh & 127) + l) & 127)] = a0 + a1 + a2 + a3;
        }
        __syncthreads();
        for (int k = 0; k < 32; ++k) {
            int idx = k * 256 + t;
            int row = idx >> 7, c = idx & 127;
            inp[(size_t)(r0 + row) * HH + 128 * ph + c] = smem[row * 128 + ((c + row) & 127)];
        }
        __syncthreads();
    }
}

// ---------------------------------------------------------------------------
// Kernel B: persistent recurrence — round-6 structure (best measured B:
// 1117us) with ONE change: v_dot2_f32_f16 -> v_pk_fma_f16 (__hfma2).
// Round-7 diagnosis: every structure issues exactly 384 dot2 wave-inst/SIMD/
// step (the fixed algorithmic work) and lands at ~1900 busy cy/SIMD/step;
// counts only fit if dot2 issues at ~4cy (half rate). pk_fma_f16 is the
// instruction behind CDNA's 2x-FP32 FP16 vector rate -> best full-rate
// candidate: same MACs in half the issue cycles if true.
// f16 pair-accumulation: 8 accumulators/gate (8 products/slot, ~1e-3 slot
// error); LTC update is contractive (gain 1-DT*ti*cm < 1) so accum error is
// stationary ~3-6e-3, not a random walk (same mechanism that keeps the
// existing f16-weight error at 0.03125).
// ---------------------------------------------------------------------------
__global__ __launch_bounds__(512)
void ltc_recurrent(const float* __restrict__ W_rec,
                   const float* __restrict__ W_cg,  const float* __restrict__ b_cg,
                   const float* __restrict__ W_eg,  const float* __restrict__ b_eg,
                   const float* __restrict__ tau,
                   float* __restrict__ st)          // [B,S,H]: inp staged in, states out
{
    const int b = blockIdx.x, t = threadIdx.x;
    const int r = t >> 1, half = t & 1;

    // [buf][132]: dwords 0..63 = packed pairs 0..63, pad 64..67, 68..131 = pairs 64..127
    __shared__ __align__(16) unsigned h_p[2][132];

    __half2 wR[64], wC[64], wE[64];
    {
        const float4* R4 = (const float4*)(W_rec + (size_t)r * HH + half * 128);
        const float4* C4 = (const float4*)(W_cg  + (size_t)r * HH + half * 128);
        const float4* E4 = (const float4*)(W_eg  + (size_t)r * HH + half * 128);
#pragma unroll
        for (int j = 0; j < 32; ++j) {
            float4 v = R4[j];
            wR[2 * j] = u2h(packh(v.x, v.y)); wR[2 * j + 1] = u2h(packh(v.z, v.w));
        }
#pragma unroll
        for (int j = 0; j < 32; ++j) {
            float4 v = C4[j];
            wC[2 * j] = u2h(packh(v.x, v.y)); wC[2 * j + 1] = u2h(packh(v.z, v.w));
        }
#pragma unroll
        for (int j = 0; j < 32; ++j) {
            float4 v = E4[j];
            wE[2 * j] = u2h(packh(v.x, v.y)); wE[2 * j + 1] = u2h(packh(v.z, v.w));
        }
    }

    const float ti = 1.0f / tau[r];
    const float bC = b_cg[r], bE = b_eg[r];

    float* stb = st + (size_t)b * SS * HH;
    float hr = 0.f;                    // f32 state for row r
    float inpC = stb[r];               // inp(0, r) — b_in+b_rec already folded

    if (t < 132) h_p[0][t] = 0u;
    bar_lds();

    for (int s = 0; s < SS; ++s) {
        float inpN = 0.f;
        if (s + 1 < SS) inpN = stb[(size_t)(s + 1) * HH + r];

        const uint4* hp4 = (const uint4*)(h_p[s & 1]) + half * 17;  // 17 uint4 = 68 dwords

        const __half2 z2 = u2h(0u);
        __half2 aR[8], aC[8], aE[8];
#pragma unroll
        for (int i = 0; i < 8; ++i) { aR[i] = z2; aC[i] = z2; aE[i] = z2; }

#pragma unroll
        for (int c = 0; c < 4; ++c) {                   // 4 chunks x 16 packed dwords
            uint4 q0 = hp4[c * 4 + 0], q1 = hp4[c * 4 + 1];
            uint4 q2 = hp4[c * 4 + 2], q3 = hp4[c * 4 + 3];
            const unsigned hw[16] = {q0.x, q0.y, q0.z, q0.w, q1.x, q1.y, q1.z, q1.w,
                                     q2.x, q2.y, q2.z, q2.w, q3.x, q3.y, q3.z, q3.w};
#pragma unroll
            for (int j = 0; j < 16; ++j) {
                const int k = c * 16 + j;
                const __half2 hv = u2h(hw[j]);
                aR[k & 7] = __hfma2(wR[k], hv, aR[k & 7]);
                aC[k & 7] = __hfma2(wC[k], hv, aC[k & 7]);
                aE[k & 7] = __hfma2(wE[k], hv, aE[k & 7]);
            }
        }

        // combine 8 f16x2 accumulators -> f32 (tree of pk_add, then unpack)
#define HSUM8(A, OUT) { \
        __half2 x01 = __hadd2(A[0], A[1]), x23 = __hadd2(A[2], A[3]); \
        __half2 x45 = __hadd2(A[4], A[5]), x67 = __hadd2(A[6], A[7]); \
        __half2 xa  = __hadd2(x01, x23),   xb  = __hadd2(x45, x67); \
        __half2 xt  = __hadd2(xa, xb); \
        OUT = __low2float(xt) + __high2float(xt); }
        float fR, fC, fE;
        HSUM8(aR, fR)
        HSUM8(aC, fC)
        HSUM8(aE, fE)
#undef HSUM8

        fR += __shfl_xor(fR, 1);                         // cross-half reduce in-wave
        fC += __shfl_xor(fC, 1);
        fE += __shfl_xor(fE, 1);

        // pointwise for row r (both half-lanes compute identical values)
        float cm = fsigmoid(fC + bC);
        float em = ftanh(fE + bE);
        float p  = inpC + fR;
        float rl = fmaxf(p, 0.f);
        float dh = (rl - hr) * ti * cm + 0.1f * em;
        hr = fmaf(0.1f, dh, hr);

        // pack rows (r, r+1): t%4==0 threads (r even, half 0) grab neighbor h
        float hnb = __shfl_xor(hr, 2);
        if ((t & 3) == 0) {
            int wi = t >> 2;                             // pair index 0..127
            int wo = wi + ((wi >> 6) << 2);              // +4 pad for pairs >= 64
            h_p[(s + 1) & 1][wo] = packh(hr, hnb);
            float2 hv2; hv2.x = hr; hv2.y = hnb;
            ((float2*)(stb + (size_t)s * HH))[wi] = hv2;
        }
        inpC = inpN;
        bar_lds();                                       // h_p[(s+1)&1] visible
    }
}

// ---------------------------------------------------------------------------
// Kernel C: outputs[row,o] = b_out[o] + states[row,:] @ W_out[o,:]
// readfirstlane scalar-W trick (round-7 verified).
// ---------------------------------------------------------------------------
__global__ __launch_bounds__(256)
void ltc_out(const float* __restrict__ states, const float* __restrict__ W_out,
             const float* __restrict__ b_out, float* __restrict__ outputs)
{
    __shared__ float smem[64 * 130];
    const int t = threadIdx.x;
    const int l = t & 63, w = t >> 6;
    const int r0 = blockIdx.x * 64;

    float osacc[32];
#pragma unroll
    for (int i = 0; i < 32; ++i)
        osacc[i] = b_out[__builtin_amdgcn_readfirstlane(32 * w + i)];

    float2* xs2 = (float2*)smem;                // [64][65] float2
    for (int ph = 0; ph < 2; ++ph) {
        for (int idx = t; idx < 64 * 64; idx += 256) {
            int row = idx >> 6, c2 = idx & 63;
            xs2[row * 65 + c2] = ((const float2*)states)[(size_t)(r0 + row) * 128 + ph * 64 + c2];
        }
        __syncthreads();
        float xr[128];
#pragma unroll
        for (int i = 0; i < 64; ++i) {
            float2 v = xs2[l * 65 + i];
            xr[2 * i] = v.x; xr[2 * i + 1] = v.y;
        }
        __syncthreads();

        for (int i = 0; i < 32; ++i) {
            const int oo = __builtin_amdgcn_readfirstlane(32 * w + i);
            const float4* wr = (const float4*)(W_out + (size_t)oo * HH + ph * 128);
            float a0 = 0.f, a1 = 0.f, a2 = 0.f, a3 = 0.f;
#pragma unroll
            for (int j = 0; j < 32; ++j) {
                float4 wv = wr[j];
                a0 = fmaf(wv.x, xr[4 * j + 0], a0);
                a1 = fmaf(wv.y, xr[4 * j + 1], a1);
                a2 = fmaf(wv.z, xr[4 * j + 2], a2);
                a3 = fmaf(wv.w, xr[4 * j + 3], a3);
            }
            osacc[i] += (a0 + a1) + (a2 + a3);
        }
    }

    __syncthreads();
#pragma unroll
    for (int i = 0; i < 32; ++i)
        smem[l * 128 + ((32 * w + i + l) & 127)] = osacc[i];
    __syncthreads();
    for (int k = 0; k < 32; ++k) {
        int idx = k * 256 + t;
        int row = idx >> 7, c = idx & 127;
        outputs[(size_t)(r0 + row) * OO + c] = smem[row * 128 + ((c + row) & 127)];
    }
}

extern "C" void kernel_launch(void* const* d_in, const int* in_sizes, int n_in,
                              void* d_out, int out_size, void* d_ws, size_t ws_size,
                              hipStream_t stream) {
    const float* x      = (const float*)d_in[0];
    const float* W_in   = (const float*)d_in[1];
    const float* b_in   = (const float*)d_in[2];
    const float* W_rec  = (const float*)d_in[3];
    const float* b_rec  = (const float*)d_in[4];
    const float* W_out  = (const float*)d_in[5];
    const float* b_out  = (const float*)d_in[6];
    const float* W_cg   = (const float*)d_in[7];
    const float* b_cg   = (const float*)d_in[8];
    const float* W_eg   = (const float*)d_in[9];
    const float* b_eg   = (const float*)d_in[10];
    const float* tau    = (const float*)d_in[11];

    float* outputs = (float*)d_out;                       // [B,S,O]
    float* states  = outputs + (size_t)BB * SS * OO;      // [B,S,H] (inp staging -> states)

    hipLaunchKernelGGL(ltc_inproj, dim3(BB * SS / 64), dim3(256), 0, stream,
                       x, W_in, b_in, b_rec, states);
    hipLaunchKernelGGL(ltc_recurrent, dim3(BB), dim3(512), 0, stream,
                       W_rec, W_cg, b_cg, W_eg, b_eg, tau, states);
    hipLaunchKernelGGL(ltc_out, dim3(BB * SS / 64), dim3(256), 0, stream,
                       states, W_out, b_out, outputs);
}